// Round 4
// baseline (738.738 us; speedup 1.0000x reference)
//
#include <hip/hip_runtime.h>

// bf16x3-split MFMA implementation.
// phi = cholT * cov * chol ; out = -chol * (tril-mask .* phi), per batch b.
// Every fp32 operand is split x = hi + lo (bf16 each); products use
// hi*hi + hi*lo + lo*hi via v_mfma_f32_16x16x32_bf16 (fp32 accumulate).

typedef short  bf16x8 __attribute__((ext_vector_type(8)));   // MFMA A/B frag: 8 bf16
typedef short  s16x4  __attribute__((ext_vector_type(4)));   // 8-byte LDS store
typedef float  f32x4  __attribute__((ext_vector_type(4)));   // MFMA C/D frag

#define MFMA(a, b, c) __builtin_amdgcn_mfma_f32_16x16x32_bf16((a), (b), (c), 0, 0, 0)

__device__ __forceinline__ short bf16hi(float x) {
    unsigned u = __float_as_uint(x);
    unsigned r = u + 0x7FFFu + ((u >> 16) & 1u);   // RNE to bf16
    return (short)(r >> 16);
}
__device__ __forceinline__ float bf2f(short h) {
    return __uint_as_float(((unsigned)(unsigned short)h) << 16);
}
__device__ __forceinline__ void split2(float x, short& h, short& l) {
    h = bf16hi(x);
    l = bf16hi(x - bf2f(h));
}

constexpr int NDIM = 128;
constexpr int LDC  = 136;   // padded row stride (bf16 elems): 272 B -> bank-stride 4, 2-way max
constexpr int LDT  = 40;    // padded row stride for tmpT (32-wide): 80 B

__launch_bounds__(512, 2)
__global__ void gauss_mfma_kernel(const float* __restrict__ muTE,
                                  const float* __restrict__ covTE,
                                  const float* __restrict__ chol,
                                  float* __restrict__ out, int batch)
{
    // ---- LDS (136 KiB total, 1 block/CU, 8 waves = 2/SIMD) ----
    // sP: phase1 = cholT hi/lo ([col][row]); phase2 = chol row-major hi/lo
    // sQ: phase1 = cov dbuf hi/lo (2x 32x136 x2) + tmpT hi/lo (128x40 x2)
    //     phase2 = phiMT hi/lo ([l][i], masked)
    __shared__ __align__(16) short sP[2][NDIM * LDC];   // 2 * 17408 shorts
    __shared__ __align__(16) short sQ[NDIM * LDC * 2];  // 34816 shorts

    short* cholT_h = &sP[0][0];
    short* cholT_l = &sP[1][0];

    const int b    = blockIdx.x;
    const int tid  = threadIdx.x;
    const int w    = tid >> 6;     // wave 0..7
    const int lane = tid & 63;
    const int li   = lane & 15;
    const int lq   = lane >> 4;    // 0..3

    const float* gChol = chol  + (size_t)b * NDIM * NDIM;
    const float* gCov  = covTE + (size_t)b * NDIM * NDIM;

    // ---- muTE passthrough ----
    if (tid < 32)
        ((f32x4*)(out + (size_t)b * NDIM))[tid] =
            ((const f32x4*)(muTE + (size_t)b * NDIM))[tid];

    // ---- phase 0: build cholT hi/lo in sP (coalesced read, scatter b16 writes) ----
    {
        const f32x4* s = (const f32x4*)gChol;
        #pragma unroll
        for (int it = 0; it < 8; ++it) {
            int v = tid + 512 * it;
            f32x4 x = s[v];
            int r  = v >> 5;             // row of chol
            int c4 = (v & 31) << 2;      // col base
            #pragma unroll
            for (int q = 0; q < 4; ++q) {
                short h, l; split2(x[q], h, l);
                cholT_h[(c4 + q) * LDC + r] = h;   // cholT[col][row]
                cholT_l[(c4 + q) * LDC + r] = l;
            }
        }
    }

    // prefetch cov chunk 0 (32x128 f32 = 1024 f32x4, 2/thread)
    f32x4 pre0, pre1;
    { const f32x4* s = (const f32x4*)gCov; pre0 = s[tid]; pre1 = s[tid + 512]; }
    __syncthreads();

    const f32x4 Z = {0.f, 0.f, 0.f, 0.f};
    f32x4 phi[8];
    #pragma unroll
    for (int t = 0; t < 8; ++t) phi[t] = Z;

    short* tmpTH = sQ + 17408;            // [128][40]
    short* tmpTL = sQ + 17408 + 5120;

    // ================= phase 1: phi += cholT_chunk^T * (cov_chunk * chol) =================
    for (int c = 0; c < 4; ++c) {
        short* cvH = sQ + (c & 1) * 8704;   // [32][136]
        short* cvL = cvH + 4352;

        // commit prefetched cov chunk as hi/lo bf16
        {
            f32x4 p[2] = {pre0, pre1};
            #pragma unroll
            for (int i = 0; i < 2; ++i) {
                int v  = tid + 512 * i;
                int j  = v >> 5;             // chunk-local row
                int c4 = (v & 31) << 2;
                s16x4 hv, lv;
                #pragma unroll
                for (int q = 0; q < 4; ++q) {
                    short h, l; split2(p[i][q], h, l);
                    hv[q] = h; lv[q] = l;
                }
                *(s16x4*)&cvH[j * LDC + c4] = hv;
                *(s16x4*)&cvL[j * LDC + c4] = lv;
            }
        }
        if (c < 3) {
            const f32x4* s = (const f32x4*)(gCov + (size_t)(c + 1) * 32 * NDIM);
            pre0 = s[tid]; pre1 = s[tid + 512];
        }
        __syncthreads();

        // ---- A2: tmp = cov_chunk(32x128) * chol(128x128); 16 D-tiles, 2/wave ----
        {
            const int ti  = w >> 2;          // 0..1
            const int tlp = (w & 3) * 2;     // 0,2,4,6
            f32x4 acc0 = Z, acc1 = Z;
            #pragma unroll
            for (int k4 = 0; k4 < 4; ++k4) {
                int ko = k4 * 32 + lq * 8;
                bf16x8 aH  = *(const bf16x8*)&cvH[(ti * 16 + li) * LDC + ko];
                bf16x8 aL  = *(const bf16x8*)&cvL[(ti * 16 + li) * LDC + ko];
                bf16x8 b0H = *(const bf16x8*)&cholT_h[(tlp * 16 + li) * LDC + ko];
                bf16x8 b0L = *(const bf16x8*)&cholT_l[(tlp * 16 + li) * LDC + ko];
                bf16x8 b1H = *(const bf16x8*)&cholT_h[((tlp + 1) * 16 + li) * LDC + ko];
                bf16x8 b1L = *(const bf16x8*)&cholT_l[((tlp + 1) * 16 + li) * LDC + ko];
                acc0 = MFMA(aH, b0H, acc0); acc0 = MFMA(aH, b0L, acc0); acc0 = MFMA(aL, b0H, acc0);
                acc1 = MFMA(aH, b1H, acc1); acc1 = MFMA(aH, b1L, acc1); acc1 = MFMA(aL, b1H, acc1);
            }
            // write tmp transposed: tmpT[l][j_local], split hi/lo
            #pragma unroll
            for (int u = 0; u < 2; ++u) {
                f32x4 a = u ? acc1 : acc0;
                int col = (tlp + u) * 16 + li;
                int r0  = ti * 16 + lq * 4;
                s16x4 hv, lv;
                #pragma unroll
                for (int r = 0; r < 4; ++r) { short h, l; split2(a[r], h, l); hv[r] = h; lv[r] = l; }
                *(s16x4*)&tmpTH[col * LDT + r0] = hv;
                *(s16x4*)&tmpTL[col * LDT + r0] = lv;
            }
        }
        __syncthreads();

        // ---- A3: phi[i][l] += sum_{j in chunk} cholT[i][j] * tmp[j][l]; wave w: i-block w ----
        {
            int ko = c * 32 + lq * 8;
            bf16x8 aH = *(const bf16x8*)&cholT_h[(w * 16 + li) * LDC + ko];
            bf16x8 aL = *(const bf16x8*)&cholT_l[(w * 16 + li) * LDC + ko];
            #pragma unroll
            for (int tl = 0; tl < 8; ++tl) {
                bf16x8 bH = *(const bf16x8*)&tmpTH[(tl * 16 + li) * LDT + lq * 8];
                bf16x8 bL = *(const bf16x8*)&tmpTL[(tl * 16 + li) * LDT + lq * 8];
                phi[tl] = MFMA(aH, bH, phi[tl]);
                phi[tl] = MFMA(aH, bL, phi[tl]);
                phi[tl] = MFMA(aL, bH, phi[tl]);
            }
        }
    }

    // prefetch chol again for phase C (L2-hot) before the barrier
    f32x4 cpre[8];
    {
        const f32x4* s = (const f32x4*)gChol;
        #pragma unroll
        for (int it = 0; it < 8; ++it) cpre[it] = s[tid + 512 * it];
    }
    __syncthreads();   // all A3 reads of sP/sQ complete

    // ================= phase B: mask phi, store transposed; rebuild chol row-major =================
    short* phiH = sQ;             // phiMT[l][i], [128][136]
    short* phiL = sQ + 17408;
    #pragma unroll
    for (int tl = 0; tl < 8; ++tl) {
        int col = tl * 16 + li;    // l
        int r0  = w * 16 + lq * 4; // i base
        s16x4 hv, lv;
        #pragma unroll
        for (int r = 0; r < 4; ++r) {
            int row = r0 + r;
            float m = (col < row) ? 1.f : (col == row ? 0.5f : 0.f);
            float v = phi[tl][r] * m;
            short h, l; split2(v, h, l);
            hv[r] = h; lv[r] = l;
        }
        *(s16x4*)&phiH[col * LDC + r0] = hv;
        *(s16x4*)&phiL[col * LDC + r0] = lv;
    }
    short* cholH = &sP[0][0];
    short* cholL = &sP[1][0];
    #pragma unroll
    for (int it = 0; it < 8; ++it) {
        int v  = tid + 512 * it;
        int r  = v >> 5;
        int c4 = (v & 31) << 2;
        s16x4 hv, lv;
        #pragma unroll
        for (int q = 0; q < 4; ++q) { short h, l; split2(cpre[it][q], h, l); hv[q] = h; lv[q] = l; }
        *(s16x4*)&cholH[r * LDC + c4] = hv;
        *(s16x4*)&cholL[r * LDC + c4] = lv;
    }
    __syncthreads();

    // ================= phase C: out = -chol * phiM; wave w: i-block w =================
    f32x4 accC[8];
    #pragma unroll
    for (int t = 0; t < 8; ++t) accC[t] = Z;

    #pragma unroll
    for (int k4 = 0; k4 < 4; ++k4) {
        int ko = k4 * 32 + lq * 8;
        bf16x8 aH = *(const bf16x8*)&cholH[(w * 16 + li) * LDC + ko];
        bf16x8 aL = *(const bf16x8*)&cholL[(w * 16 + li) * LDC + ko];
        #pragma unroll
        for (int tl = 0; tl < 8; ++tl) {
            bf16x8 bH = *(const bf16x8*)&phiH[(tl * 16 + li) * LDC + ko];
            bf16x8 bL = *(const bf16x8*)&phiL[(tl * 16 + li) * LDC + ko];
            accC[tl] = MFMA(aH, bH, accC[tl]);
            accC[tl] = MFMA(aH, bL, accC[tl]);
            accC[tl] = MFMA(aL, bH, accC[tl]);
        }
    }

    float* gOut = out + (size_t)batch * NDIM + (size_t)b * NDIM * NDIM;
    #pragma unroll
    for (int tl = 0; tl < 8; ++tl) {
        int col = tl * 16 + li;
        #pragma unroll
        for (int r = 0; r < 4; ++r) {
            int row = w * 16 + lq * 4 + r;
            gOut[row * NDIM + col] = -accC[tl][r];
        }
    }
}

extern "C" void kernel_launch(void* const* d_in, const int* in_sizes, int n_in,
                              void* d_out, int out_size, void* d_ws, size_t ws_size,
                              hipStream_t stream)
{
    const float* muTE  = (const float*)d_in[0];
    const float* covTE = (const float*)d_in[1];
    const float* chol  = (const float*)d_in[2];
    float* out = (float*)d_out;

    const int batch = in_sizes[0] / NDIM;   // 4096
    gauss_mfma_kernel<<<dim3(batch), dim3(512), 0, stream>>>(muTE, covTE, chol, out, batch);
}

// Round 5
// 697.243 us; speedup vs baseline: 1.0595x; 1.0595x over previous
//
#include <hip/hip_runtime.h>

// bf16x3-split MFMA implementation.
// phi = cholT * cov * chol ; out = -chol * (tril-mask .* phi), per batch b.
// Every fp32 operand is split x = hi + lo (bf16 each); products use
// hi*hi + hi*lo + lo*hi via v_mfma_f32_16x16x32_bf16 (fp32 accumulate).
// R5: conflict-free cholT build via swizzled f32 staging (was 16-way b16 scatter).

typedef short  bf16x8 __attribute__((ext_vector_type(8)));   // MFMA A/B frag: 8 bf16
typedef short  s16x4  __attribute__((ext_vector_type(4)));   // 8-byte LDS store
typedef short  s16x8  __attribute__((ext_vector_type(8)));   // 16-byte LDS store
typedef float  f32x4  __attribute__((ext_vector_type(4)));   // MFMA C/D frag

#define MFMA(a, b, c) __builtin_amdgcn_mfma_f32_16x16x32_bf16((a), (b), (c), 0, 0, 0)

__device__ __forceinline__ short bf16hi(float x) {
    unsigned u = __float_as_uint(x);
    unsigned r = u + 0x7FFFu + ((u >> 16) & 1u);   // RNE to bf16
    return (short)(r >> 16);
}
__device__ __forceinline__ float bf2f(short h) {
    return __uint_as_float(((unsigned)(unsigned short)h) << 16);
}
__device__ __forceinline__ void split2(float x, short& h, short& l) {
    h = bf16hi(x);
    l = bf16hi(x - bf2f(h));
}

constexpr int NDIM = 128;
constexpr int LDC  = 136;   // padded row stride (bf16 elems): 272 B -> 2-way max on b128 row reads
constexpr int LDT  = 40;    // padded row stride for tmpT (32-wide): 80 B

__launch_bounds__(512, 2)
__global__ void gauss_mfma_kernel(const float* __restrict__ muTE,
                                  const float* __restrict__ covTE,
                                  const float* __restrict__ chol,
                                  float* __restrict__ out, int batch)
{
    // ---- LDS (136 KiB total, 1 block/CU, 8 waves = 2/SIMD) ----
    __shared__ __align__(16) short sP[2][NDIM * LDC];   // cholT hi/lo -> chol row-major hi/lo
    __shared__ __align__(16) short sQ[NDIM * LDC * 2];  // stage/cov-dbuf/tmpT -> phiMT hi/lo

    short* cholT_h = &sP[0][0];
    short* cholT_l = &sP[1][0];

    const int b    = blockIdx.x;
    const int tid  = threadIdx.x;
    const int w    = tid >> 6;     // wave 0..7
    const int lane = tid & 63;
    const int li   = lane & 15;
    const int lq   = lane >> 4;    // 0..3

    const float* gChol = chol  + (size_t)b * NDIM * NDIM;
    const float* gCov  = covTE + (size_t)b * NDIM * NDIM;

    // ---- muTE passthrough ----
    if (tid < 32)
        ((f32x4*)(out + (size_t)b * NDIM))[tid] =
            ((const f32x4*)(muTE + (size_t)b * NDIM))[tid];

    // ---- phase 0a: stage chol row-major f32, XOR-swizzled 16B chunks (conflict-free) ----
    float* sStage = (float*)sQ;    // 64 KiB, sQ not yet in use
    {
        const f32x4* s = (const f32x4*)gChol;
        #pragma unroll
        for (int it = 0; it < 8; ++it) {
            int v   = tid + 512 * it;
            int r   = v >> 5;               // chol row
            int cq  = v & 31;               // 16B chunk index in row
            int cqs = cq ^ (r & 7);         // swizzle so column reads spread banks
            *(f32x4*)&sStage[r * 128 + cqs * 4] = s[v];
        }
    }

    // prefetch cov chunk 0 (hides HBM latency under the transpose)
    f32x4 pre0, pre1;
    { const f32x4* s = (const f32x4*)gCov; pre0 = s[tid]; pre1 = s[tid + 512]; }
    __syncthreads();

    // ---- phase 0b: column-read staged chol (2-way max), split, write cholT rows as 16B runs ----
    {
        #pragma unroll
        for (int s4 = 0; s4 < 4; ++s4) {
            int p  = tid + 512 * s4;
            int c  = p & 127;          // chol column = cholT row
            int r0 = (p >> 7) * 8;     // chol row base (8-aligned)
            s16x8 hv, lv;
            #pragma unroll
            for (int j = 0; j < 8; ++j) {
                int r = r0 + j;
                float x = sStage[r * 128 + ((((c >> 2) ^ (r & 7)) << 2) | (c & 3))];
                short h, l; split2(x, h, l);
                hv[j] = h; lv[j] = l;
            }
            *(s16x8*)&cholT_h[c * LDC + r0] = hv;   // contiguous 16B along cholT row
            *(s16x8*)&cholT_l[c * LDC + r0] = lv;
        }
    }
    __syncthreads();   // staging consumed (sQ free for cov) AND cholT ready

    const f32x4 Z = {0.f, 0.f, 0.f, 0.f};
    f32x4 phi[8];
    #pragma unroll
    for (int t = 0; t < 8; ++t) phi[t] = Z;

    short* tmpTH = sQ + 17408;            // [128][40]
    short* tmpTL = sQ + 17408 + 5120;

    // ================= phase 1: phi += cholT_chunk^T * (cov_chunk * chol) =================
    for (int c = 0; c < 4; ++c) {
        short* cvH = sQ + (c & 1) * 8704;   // [32][136]
        short* cvL = cvH + 4352;

        // commit prefetched cov chunk as hi/lo bf16
        {
            f32x4 p[2] = {pre0, pre1};
            #pragma unroll
            for (int i = 0; i < 2; ++i) {
                int v  = tid + 512 * i;
                int j  = v >> 5;             // chunk-local row
                int c4 = (v & 31) << 2;
                s16x4 hv, lv;
                #pragma unroll
                for (int q = 0; q < 4; ++q) {
                    short h, l; split2(p[i][q], h, l);
                    hv[q] = h; lv[q] = l;
                }
                *(s16x4*)&cvH[j * LDC + c4] = hv;
                *(s16x4*)&cvL[j * LDC + c4] = lv;
            }
        }
        if (c < 3) {
            const f32x4* s = (const f32x4*)(gCov + (size_t)(c + 1) * 32 * NDIM);
            pre0 = s[tid]; pre1 = s[tid + 512];
        }
        __syncthreads();

        // ---- A2: tmp = cov_chunk(32x128) * chol(128x128); 16 D-tiles, 2/wave ----
        {
            const int ti  = w >> 2;          // 0..1
            const int tlp = (w & 3) * 2;     // 0,2,4,6
            f32x4 acc0 = Z, acc1 = Z;
            #pragma unroll
            for (int k4 = 0; k4 < 4; ++k4) {
                int ko = k4 * 32 + lq * 8;
                bf16x8 aH  = *(const bf16x8*)&cvH[(ti * 16 + li) * LDC + ko];
                bf16x8 aL  = *(const bf16x8*)&cvL[(ti * 16 + li) * LDC + ko];
                bf16x8 b0H = *(const bf16x8*)&cholT_h[(tlp * 16 + li) * LDC + ko];
                bf16x8 b0L = *(const bf16x8*)&cholT_l[(tlp * 16 + li) * LDC + ko];
                bf16x8 b1H = *(const bf16x8*)&cholT_h[((tlp + 1) * 16 + li) * LDC + ko];
                bf16x8 b1L = *(const bf16x8*)&cholT_l[((tlp + 1) * 16 + li) * LDC + ko];
                acc0 = MFMA(aH, b0H, acc0); acc0 = MFMA(aH, b0L, acc0); acc0 = MFMA(aL, b0H, acc0);
                acc1 = MFMA(aH, b1H, acc1); acc1 = MFMA(aH, b1L, acc1); acc1 = MFMA(aL, b1H, acc1);
            }
            // write tmp transposed: tmpT[l][j_local], split hi/lo
            #pragma unroll
            for (int u = 0; u < 2; ++u) {
                f32x4 a = u ? acc1 : acc0;
                int col = (tlp + u) * 16 + li;
                int r0  = ti * 16 + lq * 4;
                s16x4 hv, lv;
                #pragma unroll
                for (int r = 0; r < 4; ++r) { short h, l; split2(a[r], h, l); hv[r] = h; lv[r] = l; }
                *(s16x4*)&tmpTH[col * LDT + r0] = hv;
                *(s16x4*)&tmpTL[col * LDT + r0] = lv;
            }
        }
        __syncthreads();

        // ---- A3: phi[i][l] += sum_{j in chunk} cholT[i][j] * tmp[j][l]; wave w: i-block w ----
        {
            int ko = c * 32 + lq * 8;
            bf16x8 aH = *(const bf16x8*)&cholT_h[(w * 16 + li) * LDC + ko];
            bf16x8 aL = *(const bf16x8*)&cholT_l[(w * 16 + li) * LDC + ko];
            #pragma unroll
            for (int tl = 0; tl < 8; ++tl) {
                bf16x8 bH = *(const bf16x8*)&tmpTH[(tl * 16 + li) * LDT + lq * 8];
                bf16x8 bL = *(const bf16x8*)&tmpTL[(tl * 16 + li) * LDT + lq * 8];
                phi[tl] = MFMA(aH, bH, phi[tl]);
                phi[tl] = MFMA(aH, bL, phi[tl]);
                phi[tl] = MFMA(aL, bH, phi[tl]);
            }
        }
    }

    // prefetch chol again for phase C (L2-hot) before the barrier
    f32x4 cpre[8];
    {
        const f32x4* s = (const f32x4*)gChol;
        #pragma unroll
        for (int it = 0; it < 8; ++it) cpre[it] = s[tid + 512 * it];
    }
    __syncthreads();   // all A3 reads of sP/sQ complete

    // ================= phase B: mask phi, store transposed; rebuild chol row-major =================
    short* phiH = sQ;             // phiMT[l][i], [128][136]
    short* phiL = sQ + 17408;
    #pragma unroll
    for (int tl = 0; tl < 8; ++tl) {
        int col = tl * 16 + li;    // l
        int r0  = w * 16 + lq * 4; // i base
        s16x4 hv, lv;
        #pragma unroll
        for (int r = 0; r < 4; ++r) {
            int row = r0 + r;
            float m = (col < row) ? 1.f : (col == row ? 0.5f : 0.f);
            float v = phi[tl][r] * m;
            short h, l; split2(v, h, l);
            hv[r] = h; lv[r] = l;
        }
        *(s16x4*)&phiH[col * LDC + r0] = hv;
        *(s16x4*)&phiL[col * LDC + r0] = lv;
    }
    short* cholH = &sP[0][0];
    short* cholL = &sP[1][0];
    #pragma unroll
    for (int it = 0; it < 8; ++it) {
        int v  = tid + 512 * it;
        int r  = v >> 5;
        int c4 = (v & 31) << 2;
        s16x4 hv, lv;
        #pragma unroll
        for (int q = 0; q < 4; ++q) { short h, l; split2(cpre[it][q], h, l); hv[q] = h; lv[q] = l; }
        *(s16x4*)&cholH[r * LDC + c4] = hv;
        *(s16x4*)&cholL[r * LDC + c4] = lv;
    }
    __syncthreads();

    // ================= phase C: out = -chol * phiM; wave w: i-block w =================
    f32x4 accC[8];
    #pragma unroll
    for (int t = 0; t < 8; ++t) accC[t] = Z;

    #pragma unroll
    for (int k4 = 0; k4 < 4; ++k4) {
        int ko = k4 * 32 + lq * 8;
        bf16x8 aH = *(const bf16x8*)&cholH[(w * 16 + li) * LDC + ko];
        bf16x8 aL = *(const bf16x8*)&cholL[(w * 16 + li) * LDC + ko];
        #pragma unroll
        for (int tl = 0; tl < 8; ++tl) {
            bf16x8 bH = *(const bf16x8*)&phiH[(tl * 16 + li) * LDC + ko];
            bf16x8 bL = *(const bf16x8*)&phiL[(tl * 16 + li) * LDC + ko];
            accC[tl] = MFMA(aH, bH, accC[tl]);
            accC[tl] = MFMA(aH, bL, accC[tl]);
            accC[tl] = MFMA(aL, bH, accC[tl]);
        }
    }

    float* gOut = out + (size_t)batch * NDIM + (size_t)b * NDIM * NDIM;
    #pragma unroll
    for (int tl = 0; tl < 8; ++tl) {
        int col = tl * 16 + li;
        #pragma unroll
        for (int r = 0; r < 4; ++r) {
            int row = w * 16 + lq * 4 + r;
            gOut[row * NDIM + col] = -accC[tl][r];
        }
    }
}

extern "C" void kernel_launch(void* const* d_in, const int* in_sizes, int n_in,
                              void* d_out, int out_size, void* d_ws, size_t ws_size,
                              hipStream_t stream)
{
    const float* muTE  = (const float*)d_in[0];
    const float* covTE = (const float*)d_in[1];
    const float* chol  = (const float*)d_in[2];
    float* out = (float*)d_out;

    const int batch = in_sizes[0] / NDIM;   // 4096
    gauss_mfma_kernel<<<dim3(batch), dim3(512), 0, stream>>>(muTE, covTE, chol, out, batch);
}